// Round 1
// baseline (1262.645 us; speedup 1.0000x reference)
//
#include <hip/hip_runtime.h>
#include <hip/hip_bf16.h>
#include <math.h>

#define D_MODEL 2048
#define VOCAB   32000
#define NTOK    8192
#define NCHUNK  (VOCAB / 64)      // 500 chunks of 64 cols

// ---- fallback (f32) path tiles ----
#define BM      128
#define BN      128
#define BK      32
#define LDK     (BK + 8)
#define MTILES  (NTOK / BM)       // 64
#define NTILES  (VOCAB / BN)      // 250

// ---- fp8 v2 (256^2 ring-4 pipeline) ----
#define BM2     256
#define BN2     256
#define SUBK    64                 // K bytes per sub-buffer
#define NSUB    (D_MODEL / SUBK)   // 32 sub-tiles
#define SUBSZ   32768              // A-sub 16KB + B-sub 16KB
#define MT2     (NTOK / BM2)       // 32
#define NT2     (VOCAB / BN2)      // 125

typedef __attribute__((ext_vector_type(8))) short  frag8;   // bf16 fallback
typedef __attribute__((ext_vector_type(4))) float  f32x4;
typedef __attribute__((ext_vector_type(4))) int    i32x4;
typedef __attribute__((ext_vector_type(8))) int    i32x8;

// ---------------- helpers ----------------

__device__ inline void g2l16(const void* g, void* l) {
    __builtin_amdgcn_global_load_lds(
        (const __attribute__((address_space(1))) unsigned int*)g,
        (__attribute__((address_space(3))) unsigned int*)l,
        16, 0, 0);
}

// pack two fp32 -> two bf16 (truncation), fallback path
__device__ inline unsigned pack_bf16(float x, float y) {
    union { float f; unsigned u; } a, b;
    a.f = x; b.f = y;
    return __builtin_amdgcn_perm(b.u, a.u, 0x07060302u);
}

// ---------------- fp32 -> fp8 e4m3 conversion (HW RNE) ----------------

__global__ void cvt_fp8_kernel(const float* __restrict__ src, unsigned char* __restrict__ dst) {
    size_t i = (size_t)blockIdx.x * 256 + threadIdx.x;   // one uint2 (8 fp8) per thread
    float4 v0 = ((const float4*)src)[2 * i];
    float4 v1 = ((const float4*)src)[2 * i + 1];
    int lo = 0, hi = 0;
    lo = __builtin_amdgcn_cvt_pk_fp8_f32(v0.x, v0.y, lo, 0);
    lo = __builtin_amdgcn_cvt_pk_fp8_f32(v0.z, v0.w, lo, 1);
    hi = __builtin_amdgcn_cvt_pk_fp8_f32(v1.x, v1.y, hi, 0);
    hi = __builtin_amdgcn_cvt_pk_fp8_f32(v1.z, v1.w, hi, 1);
    uint2 o = { (unsigned)lo, (unsigned)hi };
    ((uint2*)dst)[i] = o;
}

// ---------------- main GEMM+LSE v2: 256x256 tile, 8 waves, ring-4 K pipeline ----------------
//
// LDS (dynamic, 128 KB): 4 ring slots of SUBSZ=32KB; slot j: [A-sub 16KB][B-sub 16KB].
// Sub-buffer layout: 256 rows x 64B stored as 128 pair-lines of 128B (rows 2p,2p+1).
// Logical (rho=row&1, jj=16B-chunk 0..3) stored at slot ((rho<<2)|jj) ^ (p&7) within the
// line -> every ds_read_b128 spreads evenly over all 8 bank-quads. global_load_lds dest
// stays linear (wave-uniform base + lane*16); the permutation is applied to the GLOBAL
// source address (guide G21: both-sides-or-neither).
//
// Pipeline: consume subs (2t,2t+1) while subs (2t+2,2t+3) are in flight; stage (2t+4,2t+5)
// after all waves' reads of their slots are done (lgkmcnt(0)+barrier). Main-loop wait is
// s_waitcnt vmcnt(8) (counted, never drains); only the last iteration uses vmcnt(0).

__global__ __launch_bounds__(512, 2)
void gemm_lse_fp8_v2(const unsigned char* __restrict__ Hq, const unsigned char* __restrict__ Wq,
                     float* __restrict__ partials) {
    extern __shared__ unsigned char lds[];

    // bijective XCD swizzle: 4000 = 8*500
    const int L     = (blockIdx.x & 7) * 500 + (blockIdx.x >> 3);
    const int mtile = L & 31;           // ntile-major for W reuse
    const int ntile = L >> 5;
    const int m0 = mtile * BM2;
    const int n0 = ntile * BN2;

    const int tid  = threadIdx.x;
    const int lane = tid & 63;
    const int w    = tid >> 6;          // 0..7
    const int wr   = w >> 2;            // 0..1 : row half (128 rows)
    const int wc   = w & 3;             // 0..3 : col quarter (64 cols)
    const int q    = lane >> 4;         // 0..3 : K-part of fragment
    const int c    = lane & 15;         // row-within-16 of fragment

    // ---- staging lane constants (pair-line swizzled source) ----
    const int sline = tid >> 3;                      // 0..63 pair-line within call
    const int sp    = (tid & 7) ^ (sline & 7);       // logical content of my slot
    const int srow  = 2 * sline + (sp >> 2);         // global row within 128-row half
    const int sjj   = sp & 3;                        // 16B chunk within 64B K-sub
    const unsigned char* gA = Hq + (size_t)(m0 + srow) * D_MODEL + sjj * 16;
    const unsigned char* gB = Wq + (size_t)(n0 + srow) * D_MODEL + sjj * 16;
    const unsigned wbase = (unsigned)w * 1024;       // wave-uniform LDS dest base

    // ---- fragment-read lane constants ----
    const int prow = c >> 1;
    const int qh   = q >> 1;            // 0: even sub, 1: odd sub
    const int qb   = q & 1;
    const unsigned sA    = (unsigned)((((c & 1) << 2) | (qb << 1)) ^ prow) << 4; // slot*16, h=0
    const unsigned aoff0 = (unsigned)(wr * 64 + prow) * 128 + sA;
    const unsigned aoff1 = aoff0 ^ 16;
    const unsigned boff0 = 16384u + (unsigned)(wc * 32 + prow) * 128 + sA;
    const unsigned boff1 = boff0 ^ 16;

    f32x4 acc[8][4];
    const f32x4 zero = {0.f, 0.f, 0.f, 0.f};
    #pragma unroll
    for (int i = 0; i < 8; ++i)
        #pragma unroll
        for (int j = 0; j < 4; ++j) acc[i][j] = zero;

    auto STAGE = [&](int s) {   // stage K-sub s into ring slot s&3 (4 vmem instrs/wave)
        const unsigned base = (unsigned)(s & 3) * (unsigned)SUBSZ;
        const size_t ko = (size_t)s * SUBK;
        g2l16(gA + ko,                           lds + base + wbase);
        g2l16(gA + ko + (size_t)128 * D_MODEL,   lds + base + 8192 + wbase);
        g2l16(gB + ko,                           lds + base + 16384 + wbase);
        g2l16(gB + ko + (size_t)128 * D_MODEL,   lds + base + 24576 + wbase);
    };

    // prologue: fill all 4 ring slots (16 vmem instrs in flight)
    STAGE(0); STAGE(1); STAGE(2); STAGE(3);

    union Frag { i32x8 v; i32x4 h[2]; };

    #pragma unroll 1
    for (int t = 0; t < 16; ++t) {
        // subs (2t, 2t+1) ready once everything older than the newest 8 vmem ops retired
        if (t == 15) asm volatile("s_waitcnt vmcnt(0)" ::: "memory");
        else         asm volatile("s_waitcnt vmcnt(8)" ::: "memory");
        __builtin_amdgcn_s_barrier();           // all waves' staging of (2t,2t+1) done

        const unsigned ring   = (unsigned)(t & 1) * (2u * SUBSZ);
        const unsigned subsel = ring + (unsigned)qh * SUBSZ;
        const unsigned char* a0 = lds + subsel + aoff0;
        const unsigned char* a1 = lds + subsel + aoff1;
        const unsigned char* b0 = lds + subsel + boff0;
        const unsigned char* b1 = lds + subsel + boff1;

        i32x8 a8[8], b8[4];
        #pragma unroll
        for (int ni = 0; ni < 4; ++ni) {
            Frag f;
            f.h[0] = *(const i32x4*)(b0 + ni * 1024);
            f.h[1] = *(const i32x4*)(b1 + ni * 1024);
            b8[ni] = f.v;
        }
        #pragma unroll
        for (int mi = 0; mi < 8; ++mi) {
            Frag f;
            f.h[0] = *(const i32x4*)(a0 + mi * 1024);
            f.h[1] = *(const i32x4*)(a1 + mi * 1024);
            a8[mi] = f.v;
        }

        // all my LDS reads complete before signaling; then slots (2t,2t+1) are free
        asm volatile("s_waitcnt lgkmcnt(0)" ::: "memory");
        __builtin_amdgcn_sched_barrier(0);
        __builtin_amdgcn_s_barrier();           // all waves' reads done -> safe to overwrite

        if (t < 14) { STAGE(2 * t + 4); STAGE(2 * t + 5); }   // lands during MFMA below

        __builtin_amdgcn_s_setprio(1);
        #pragma unroll
        for (int mi = 0; mi < 8; ++mi)
            #pragma unroll
            for (int ni = 0; ni < 4; ++ni)
                acc[mi][ni] = __builtin_amdgcn_mfma_scale_f32_16x16x128_f8f6f4(
                    a8[mi], b8[ni], acc[mi][ni],
                    0, 0,                       // fp8 e4m3 / fp8 e4m3
                    0, 0x7F7F7F7F,              // scale_a = 1.0 (E8M0 127)
                    0, 0x7F7F7F7F);             // scale_b = 1.0
        __builtin_amdgcn_s_setprio(0);
    }

    // epilogue: per-row max & sum(exp) over this wave's 64 columns
    // C/D layout (16x16): col = lane&15, row = (lane>>4)*4 + reg
    const int chunk = ntile * 4 + wc;
    #pragma unroll
    for (int mi = 0; mi < 8; ++mi) {
        #pragma unroll
        for (int r = 0; r < 4; ++r) {
            float v0 = acc[mi][0][r], v1 = acc[mi][1][r];
            float v2 = acc[mi][2][r], v3 = acc[mi][3][r];
            float mx = fmaxf(fmaxf(v0, v1), fmaxf(v2, v3));
            #pragma unroll
            for (int mask = 1; mask <= 8; mask <<= 1)
                mx = fmaxf(mx, __shfl_xor(mx, mask, 64));
            float sm = __expf(v0 - mx) + __expf(v1 - mx)
                     + __expf(v2 - mx) + __expf(v3 - mx);
            #pragma unroll
            for (int mask = 1; mask <= 8; mask <<= 1)
                sm += __shfl_xor(sm, mask, 64);
            if (c == 0) {
                int row_g = m0 + wr * 128 + mi * 16 + q * 4 + r;
                float* p = partials + ((size_t)row_g * NCHUNK + chunk) * 2;
                p[0] = mx;
                p[1] = sm;
            }
        }
    }
}

// ---------------- fallback GEMM (fp32 in-flight bf16 pack) ----------------

__global__ __launch_bounds__(256, 2)
void gemm_lse_f32(const float* __restrict__ H, const float* __restrict__ W,
                  float* __restrict__ partials) {
    __shared__ unsigned short As[BM][LDK];
    __shared__ unsigned short Bs[BN][LDK];

    const int GM = 8;
    int bid   = blockIdx.x;
    int super = bid / (GM * NTILES);
    int rem   = bid % (GM * NTILES);
    int mtile = super * GM + (rem % GM);
    int ntile = rem / GM;

    const int m0 = mtile * BM;
    const int n0 = ntile * BN;

    const int tid  = threadIdx.x;
    const int lane = tid & 63;
    const int w    = tid >> 6;
    const int wm   = (w >> 1) * 64;
    const int wn   = (w & 1)  * 64;
    const int q    = lane >> 4;
    const int c    = lane & 15;

    f32x4 acc[4][4];
    const f32x4 zero = {0.f, 0.f, 0.f, 0.f};
    #pragma unroll
    for (int i = 0; i < 4; ++i)
        #pragma unroll
        for (int j = 0; j < 4; ++j) acc[i][j] = zero;

    for (int kt = 0; kt < D_MODEL / BK; ++kt) {
        const int k0 = kt * BK;
        #pragma unroll
        for (int s = 0; s < 4; ++s) {
            int i   = tid + s * 256;
            int row = i >> 3;
            int kq  = (i & 7) << 2;

            const float4* pa = (const float4*)(H + (size_t)(m0 + row) * D_MODEL + k0 + kq);
            float4 va = *pa;
            uint2 ba = { pack_bf16(va.x, va.y), pack_bf16(va.z, va.w) };
            *(uint2*)&As[row][kq] = ba;

            const float4* pb = (const float4*)(W + (size_t)(n0 + row) * D_MODEL + k0 + kq);
            float4 vb = *pb;
            uint2 bb = { pack_bf16(vb.x, vb.y), pack_bf16(vb.z, vb.w) };
            *(uint2*)&Bs[row][kq] = bb;
        }
        __syncthreads();

        frag8 af[4], bf[4];
        #pragma unroll
        for (int t = 0; t < 4; ++t)
            af[t] = *(const frag8*)&As[wm + t * 16 + c][q * 8];
        #pragma unroll
        for (int t = 0; t < 4; ++t)
            bf[t] = *(const frag8*)&Bs[wn + t * 16 + c][q * 8];

        #pragma unroll
        for (int tm = 0; tm < 4; ++tm)
            #pragma unroll
            for (int tn = 0; tn < 4; ++tn)
                acc[tm][tn] = __builtin_amdgcn_mfma_f32_16x16x32_bf16(
                    af[tm], bf[tn], acc[tm][tn], 0, 0, 0);
        __syncthreads();
    }

    const int chunk = ntile * 2 + (w & 1);
    #pragma unroll
    for (int tm = 0; tm < 4; ++tm) {
        #pragma unroll
        for (int r = 0; r < 4; ++r) {
            float v0 = acc[tm][0][r], v1 = acc[tm][1][r];
            float v2 = acc[tm][2][r], v3 = acc[tm][3][r];
            float mx = fmaxf(fmaxf(v0, v1), fmaxf(v2, v3));
            #pragma unroll
            for (int mask = 1; mask <= 8; mask <<= 1)
                mx = fmaxf(mx, __shfl_xor(mx, mask, 64));
            float sm = __expf(v0 - mx) + __expf(v1 - mx)
                     + __expf(v2 - mx) + __expf(v3 - mx);
            #pragma unroll
            for (int mask = 1; mask <= 8; mask <<= 1)
                sm += __shfl_xor(sm, mask, 64);
            if (c == 0) {
                int row_g = m0 + wm + tm * 16 + q * 4 + r;
                float* p = partials + ((size_t)row_g * NCHUNK + chunk) * 2;
                p[0] = mx;
                p[1] = sm;
            }
        }
    }
}

// ---------------- aux kernels (no global atomics anywhere) ----------------

// one WAVE per token: exact fp32 dot(h[n], w[target[n]])
__global__ __launch_bounds__(256)
void tgt_kernel(const float* __restrict__ H, const float* __restrict__ W,
                const int* __restrict__ targets, float* __restrict__ tgt_logit) {
    int token = blockIdx.x * 4 + (threadIdx.x >> 6);
    int lane  = threadIdx.x & 63;

    int t  = targets[token];
    int tt = (t == -100) ? 0 : t;
    const float4* h  = (const float4*)(H + (size_t)token * D_MODEL);
    const float4* wr = (const float4*)(W + (size_t)tt * D_MODEL);
    float p = 0.f;
    #pragma unroll
    for (int j = lane; j < D_MODEL / 4; j += 64) {
        float4 a = h[j], b = wr[j];
        p += a.x * b.x + a.y * b.y + a.z * b.z + a.w * b.w;
    }
    #pragma unroll
    for (int mask = 1; mask < 64; mask <<= 1)
        p += __shfl_xor(p, mask, 64);
    if (lane == 0) tgt_logit[token] = p;
}

__device__ inline void lse_merge(float& m, float& s, float om, float os) {
    if (om > m) { s = s * __expf(m - om) + os; m = om; }
    else        { s += os * __expf(om - m); }
}

// one WAVE per token: merge 500 (m,s) chunks -> nll[token]; no atomics
__global__ __launch_bounds__(256)
void reduce_kernel(const float* __restrict__ partials,
                   const float* __restrict__ tgt_logit,
                   const int* __restrict__ targets,
                   float* __restrict__ nll) {
    int token = blockIdx.x * 4 + (threadIdx.x >> 6);
    int lane  = threadIdx.x & 63;

    float m = -INFINITY, s = 0.f;
    const float* base = partials + (size_t)token * NCHUNK * 2;
    for (int ch = lane; ch < NCHUNK; ch += 64) {
        float2 p = ((const float2*)base)[ch];
        lse_merge(m, s, p.x, p.y);
    }
    #pragma unroll
    for (int mask = 1; mask < 64; mask <<= 1) {
        float om = __shfl_xor(m, mask, 64);
        float os = __shfl_xor(s, mask, 64);
        lse_merge(m, s, om, os);
    }
    if (lane == 0) {
        int t = targets[token];
        nll[token] = (t != -100) ? (m + __logf(s) - tgt_logit[token]) : 0.0f;
    }
}

// single block: sum nll + count valid, divide
__global__ __launch_bounds__(256)
void final_kernel(const float* __restrict__ nll, const int* __restrict__ targets,
                  float* __restrict__ out) {
    int tid = threadIdx.x;
    float sum = 0.f, cnt = 0.f;
    for (int i = tid; i < NTOK; i += 256) {
        sum += nll[i];
        cnt += (targets[i] != -100) ? 1.0f : 0.0f;
    }
    #pragma unroll
    for (int mask = 1; mask < 64; mask <<= 1) {
        sum += __shfl_xor(sum, mask, 64);
        cnt += __shfl_xor(cnt, mask, 64);
    }
    __shared__ float lsum[4], lcnt[4];
    int lane = tid & 63, wid = tid >> 6;
    if (lane == 0) { lsum[wid] = sum; lcnt[wid] = cnt; }
    __syncthreads();
    if (tid == 0) {
        float S = lsum[0] + lsum[1] + lsum[2] + lsum[3];
        float C = lcnt[0] + lcnt[1] + lcnt[2] + lcnt[3];
        out[0] = (C > 0.f) ? (S / C) : 0.f;
    }
}

// ---------------- launch ----------------

extern "C" void kernel_launch(void* const* d_in, const int* in_sizes, int n_in,
                              void* d_out, int out_size, void* d_ws, size_t ws_size,
                              hipStream_t stream) {
    (void)in_sizes; (void)n_in; (void)out_size;
    const float* H       = (const float*)d_in[0];   // [4,2048,2048]
    const int*   targets = (const int*)d_in[1];     // [8192]
    const float* W       = (const float*)d_in[2];   // [32000,2048]
    float*       out     = (float*)d_out;

    char* ws = (char*)d_ws;
    const size_t H8_BYTES   = (size_t)NTOK  * D_MODEL;           //  16 MB
    const size_t W8_BYTES   = (size_t)VOCAB * D_MODEL;           //  64 MB
    const size_t PART_BYTES = (size_t)NTOK * NCHUNK * 2 * 4;     //  32 MB
    const size_t NEED = H8_BYTES + W8_BYTES + PART_BYTES + (size_t)NTOK * 8 + 64;

    if (ws_size >= NEED) {
        unsigned char* Hq = (unsigned char*)ws;
        unsigned char* Wq = (unsigned char*)(ws + H8_BYTES);
        float* partials   = (float*)(ws + H8_BYTES + W8_BYTES);
        float* tgt_logit  = (float*)(ws + H8_BYTES + W8_BYTES + PART_BYTES);
        float* nll        = tgt_logit + NTOK;

        static bool attr_done = false;
        if (!attr_done) {
            (void)hipFuncSetAttribute(reinterpret_cast<const void*>(gemm_lse_fp8_v2),
                                      hipFuncAttributeMaxDynamicSharedMemorySize, 131072);
            attr_done = true;
        }

        cvt_fp8_kernel<<<(NTOK  * D_MODEL / 8) / 256, 256, 0, stream>>>(H, Hq);
        cvt_fp8_kernel<<<(VOCAB * D_MODEL / 8) / 256, 256, 0, stream>>>(W, Wq);
        gemm_lse_fp8_v2<<<MT2 * NT2, 512, 131072, stream>>>(Hq, Wq, partials);
        tgt_kernel<<<NTOK / 4, 256, 0, stream>>>(H, W, targets, tgt_logit);
        reduce_kernel<<<NTOK / 4, 256, 0, stream>>>(partials, tgt_logit, targets, nll);
        final_kernel<<<1, 256, 0, stream>>>(nll, targets, out);
    } else {
        float* partials  = (float*)ws;
        float* tgt_logit = (float*)(ws + PART_BYTES);
        float* nll       = tgt_logit + NTOK;

        gemm_lse_f32<<<MTILES * NTILES, 256, 0, stream>>>(H, W, partials);
        tgt_kernel<<<NTOK / 4, 256, 0, stream>>>(H, W, targets, tgt_logit);
        reduce_kernel<<<NTOK / 4, 256, 0, stream>>>(partials, tgt_logit, targets, nll);
        final_kernel<<<1, 256, 0, stream>>>(nll, targets, out);
    }
}

// Round 2
// 1170.946 us; speedup vs baseline: 1.0783x; 1.0783x over previous
//
#include <hip/hip_runtime.h>
#include <hip/hip_bf16.h>
#include <math.h>

#define D_MODEL 2048
#define VOCAB   32000
#define NTOK    8192
#define NCHUNK  (VOCAB / 64)      // 500 chunks of 64 cols

// ---- fallback (f32) path tiles ----
#define BM      128
#define BN      128
#define BK      32
#define LDK     (BK + 8)
#define MTILES  (NTOK / BM)       // 64
#define NTILES  (VOCAB / BN)      // 250

// ---- fp8 (256^2 ring-4, 4-phase interleave) ----
#define BM2     256
#define BN2     256
#define SUBK    64                 // K bytes per sub-buffer
#define NSUB    (D_MODEL / SUBK)   // 32 sub-tiles
#define SUBSZ   32768              // A-sub 16KB + B-sub 16KB
#define MT2     (NTOK / BM2)       // 32
#define NT2     (VOCAB / BN2)      // 125

typedef __attribute__((ext_vector_type(8))) short  frag8;   // bf16 fallback
typedef __attribute__((ext_vector_type(4))) float  f32x4;
typedef __attribute__((ext_vector_type(4))) int    i32x4;
typedef __attribute__((ext_vector_type(8))) int    i32x8;

// ---------------- helpers ----------------

__device__ inline void g2l16(const void* g, void* l) {
    __builtin_amdgcn_global_load_lds(
        (const __attribute__((address_space(1))) unsigned int*)g,
        (__attribute__((address_space(3))) unsigned int*)l,
        16, 0, 0);
}

// pack two fp32 -> two bf16 (truncation), fallback path
__device__ inline unsigned pack_bf16(float x, float y) {
    union { float f; unsigned u; } a, b;
    a.f = x; b.f = y;
    return __builtin_amdgcn_perm(b.u, a.u, 0x07060302u);
}

// ---------------- fp32 -> fp8 e4m3 conversion (HW RNE) ----------------

__global__ void cvt_fp8_kernel(const float* __restrict__ src, unsigned char* __restrict__ dst) {
    size_t i = (size_t)blockIdx.x * 256 + threadIdx.x;   // one uint2 (8 fp8) per thread
    float4 v0 = ((const float4*)src)[2 * i];
    float4 v1 = ((const float4*)src)[2 * i + 1];
    int lo = 0, hi = 0;
    lo = __builtin_amdgcn_cvt_pk_fp8_f32(v0.x, v0.y, lo, 0);
    lo = __builtin_amdgcn_cvt_pk_fp8_f32(v0.z, v0.w, lo, 1);
    hi = __builtin_amdgcn_cvt_pk_fp8_f32(v1.x, v1.y, hi, 0);
    hi = __builtin_amdgcn_cvt_pk_fp8_f32(v1.z, v1.w, hi, 1);
    uint2 o = { (unsigned)lo, (unsigned)hi };
    ((uint2*)dst)[i] = o;
}

// ---------------- main GEMM+LSE v3: 256x256, 8 waves, ring-4, 4-phase schedule ----------------
//
// Staging/layout identical to v2 (verified): ring of 4 slots x 32KB; pair-line swizzle
// applied on the GLOBAL source address, LDS dest linear (G21). vmcnt(8) counted wait.
//
// NEW vs v2: the per-iteration compute is split into 4 phases in the m201 style:
//   P0: ds_read all 4 B-frags + A-frags 0,1 (12 reads); BAR; lgkmcnt(0); 8 MFMA; BAR
//   P1: A-frags 2,3 (4 reads);                          BAR; lgkmcnt(0); 8 MFMA; BAR
//   P2: A-frags 4,5;                                    BAR; lgkmcnt(0); 8 MFMA; BAR
//   P3: A-frags 6,7; lgkmcnt(0); BAR (all waves' reads of slots done); STAGE next;
//       8 MFMA;  (next iteration opens with vmcnt+BAR)
// 8 barriers per K=128B -- same sync density as the verified 256^2 8-phase template.
// The 2-barrier-per-phase alternation lets the LDS-read window of one wave overlap the
// MFMA window of the other wave on the same SIMD (T3), which makes setprio (T5) active.

__global__ __launch_bounds__(512, 2)
void gemm_lse_fp8_v2(const unsigned char* __restrict__ Hq, const unsigned char* __restrict__ Wq,
                     float* __restrict__ partials) {
    extern __shared__ unsigned char lds[];

    // bijective XCD swizzle (4000 = 8*500), then 2D supertile decode:
    // within an XCD chunk, mtile cycles through 8 values fastest, ntile sweeps.
    // Concurrent working set per XCD: 8 A-panels (4MB) + ~4 B-panels (2MB).
    const int L  = (blockIdx.x & 7) * 500 + (blockIdx.x >> 3);
    const int qs = L / 1000;                 // 0..3  (mtile group)
    const int rs = L % 1000;
    const int mtile = (rs & 7) + qs * 8;     // 0..31
    const int ntile = (rs >> 3) % 125;       // 0..124  (bijective: rs>>3 <= 124)
    const int m0 = mtile * BM2;
    const int n0 = ntile * BN2;

    const int tid  = threadIdx.x;
    const int lane = tid & 63;
    const int w    = tid >> 6;          // 0..7
    const int wr   = w >> 2;            // 0..1 : row half (128 rows)
    const int wc   = w & 3;             // 0..3 : col quarter (64 cols)
    const int q    = lane >> 4;         // 0..3 : K-part of fragment
    const int c    = lane & 15;         // row-within-16 of fragment

    // ---- staging lane constants (pair-line swizzled source) ----
    const int sline = tid >> 3;                      // 0..63 pair-line within call
    const int sp    = (tid & 7) ^ (sline & 7);       // logical content of my slot
    const int srow  = 2 * sline + (sp >> 2);         // global row within 128-row half
    const int sjj   = sp & 3;                        // 16B chunk within 64B K-sub
    const unsigned char* gA = Hq + (size_t)(m0 + srow) * D_MODEL + sjj * 16;
    const unsigned char* gB = Wq + (size_t)(n0 + srow) * D_MODEL + sjj * 16;
    const unsigned wbase = (unsigned)w * 1024;       // wave-uniform LDS dest base

    // ---- fragment-read lane constants ----
    const int prow = c >> 1;
    const int qh   = q >> 1;            // 0: even sub, 1: odd sub
    const int qb   = q & 1;
    const unsigned sA    = (unsigned)((((c & 1) << 2) | (qb << 1)) ^ prow) << 4; // slot*16
    const unsigned aoff0 = (unsigned)(wr * 64 + prow) * 128 + sA;
    const unsigned aoff1 = aoff0 ^ 16;
    const unsigned boff0 = 16384u + (unsigned)(wc * 32 + prow) * 128 + sA;
    const unsigned boff1 = boff0 ^ 16;

    f32x4 acc[8][4];
    const f32x4 zero = {0.f, 0.f, 0.f, 0.f};
    #pragma unroll
    for (int i = 0; i < 8; ++i)
        #pragma unroll
        for (int j = 0; j < 4; ++j) acc[i][j] = zero;

    auto STAGE = [&](int s) {   // stage K-sub s into ring slot s&3 (4 vmem instrs/wave)
        const unsigned base = (unsigned)(s & 3) * (unsigned)SUBSZ;
        const size_t ko = (size_t)s * SUBK;
        g2l16(gA + ko,                           lds + base + wbase);
        g2l16(gA + ko + (size_t)128 * D_MODEL,   lds + base + 8192 + wbase);
        g2l16(gB + ko,                           lds + base + 16384 + wbase);
        g2l16(gB + ko + (size_t)128 * D_MODEL,   lds + base + 24576 + wbase);
    };

    // prologue: fill all 4 ring slots (16 vmem instrs in flight)
    STAGE(0); STAGE(1); STAGE(2); STAGE(3);

    union Frag { i32x8 v; i32x4 h[2]; };

    #pragma unroll 1
    for (int t = 0; t < 16; ++t) {
        // subs (2t, 2t+1) resident once the oldest 8 vmem ops retired
        if (t == 15) asm volatile("s_waitcnt vmcnt(0)" ::: "memory");
        else         asm volatile("s_waitcnt vmcnt(8)" ::: "memory");
        __builtin_amdgcn_s_barrier();

        const unsigned ring   = (unsigned)(t & 1) * (2u * SUBSZ);
        const unsigned subsel = ring + (unsigned)qh * SUBSZ;
        const unsigned char* a0 = lds + subsel + aoff0;
        const unsigned char* a1 = lds + subsel + aoff1;
        const unsigned char* b0 = lds + subsel + boff0;
        const unsigned char* b1 = lds + subsel + boff1;

        i32x8 b8[4], fa, fb;

        // ---------------- P0: all B + A0,A1 ----------------
        #pragma unroll
        for (int ni = 0; ni < 4; ++ni) {
            Frag f;
            f.h[0] = *(const i32x4*)(b0 + ni * 1024);
            f.h[1] = *(const i32x4*)(b1 + ni * 1024);
            b8[ni] = f.v;
        }
        {
            Frag f0, f1;
            f0.h[0] = *(const i32x4*)(a0 + 0 * 1024);
            f0.h[1] = *(const i32x4*)(a1 + 0 * 1024);
            f1.h[0] = *(const i32x4*)(a0 + 1 * 1024);
            f1.h[1] = *(const i32x4*)(a1 + 1 * 1024);
            fa = f0.v; fb = f1.v;
        }
        asm volatile("s_waitcnt lgkmcnt(8)" ::: "memory");
        __builtin_amdgcn_s_barrier();
        asm volatile("s_waitcnt lgkmcnt(0)" ::: "memory");
        __builtin_amdgcn_sched_barrier(0);
        __builtin_amdgcn_s_setprio(1);
        #pragma unroll
        for (int ni = 0; ni < 4; ++ni)
            acc[0][ni] = __builtin_amdgcn_mfma_scale_f32_16x16x128_f8f6f4(
                fa, b8[ni], acc[0][ni], 0, 0, 0, 0x7F7F7F7F, 0, 0x7F7F7F7F);
        #pragma unroll
        for (int ni = 0; ni < 4; ++ni)
            acc[1][ni] = __builtin_amdgcn_mfma_scale_f32_16x16x128_f8f6f4(
                fb, b8[ni], acc[1][ni], 0, 0, 0, 0x7F7F7F7F, 0, 0x7F7F7F7F);
        __builtin_amdgcn_s_setprio(0);
        __builtin_amdgcn_s_barrier();

        // ---------------- P1, P2: A-frag pairs ----------------
        #pragma unroll
        for (int p = 1; p < 3; ++p) {
            Frag f0, f1;
            f0.h[0] = *(const i32x4*)(a0 + (2 * p) * 1024);
            f0.h[1] = *(const i32x4*)(a1 + (2 * p) * 1024);
            f1.h[0] = *(const i32x4*)(a0 + (2 * p + 1) * 1024);
            f1.h[1] = *(const i32x4*)(a1 + (2 * p + 1) * 1024);
            fa = f0.v; fb = f1.v;
            __builtin_amdgcn_s_barrier();
            asm volatile("s_waitcnt lgkmcnt(0)" ::: "memory");
            __builtin_amdgcn_sched_barrier(0);
            __builtin_amdgcn_s_setprio(1);
            #pragma unroll
            for (int ni = 0; ni < 4; ++ni)
                acc[2 * p][ni] = __builtin_amdgcn_mfma_scale_f32_16x16x128_f8f6f4(
                    fa, b8[ni], acc[2 * p][ni], 0, 0, 0, 0x7F7F7F7F, 0, 0x7F7F7F7F);
            #pragma unroll
            for (int ni = 0; ni < 4; ++ni)
                acc[2 * p + 1][ni] = __builtin_amdgcn_mfma_scale_f32_16x16x128_f8f6f4(
                    fb, b8[ni], acc[2 * p + 1][ni], 0, 0, 0, 0x7F7F7F7F, 0, 0x7F7F7F7F);
            __builtin_amdgcn_s_setprio(0);
            __builtin_amdgcn_s_barrier();
        }

        // ---------------- P3: A6,A7 + stage next tile into freed slots ----------------
        {
            Frag f0, f1;
            f0.h[0] = *(const i32x4*)(a0 + 6 * 1024);
            f0.h[1] = *(const i32x4*)(a1 + 6 * 1024);
            f1.h[0] = *(const i32x4*)(a0 + 7 * 1024);
            f1.h[1] = *(const i32x4*)(a1 + 7 * 1024);
            fa = f0.v; fb = f1.v;
        }
        asm volatile("s_waitcnt lgkmcnt(0)" ::: "memory");   // my reads of slots done
        __builtin_amdgcn_s_barrier();                        // ALL waves' reads done
        __builtin_amdgcn_sched_barrier(0);                   // keep STAGE below the barrier
        if (t < 14) { STAGE(2 * t + 4); STAGE(2 * t + 5); }  // overwrite freed slots
        __builtin_amdgcn_sched_barrier(0);
        __builtin_amdgcn_s_setprio(1);
        #pragma unroll
        for (int ni = 0; ni < 4; ++ni)
            acc[6][ni] = __builtin_amdgcn_mfma_scale_f32_16x16x128_f8f6f4(
                fa, b8[ni], acc[6][ni], 0, 0, 0, 0x7F7F7F7F, 0, 0x7F7F7F7F);
        #pragma unroll
        for (int ni = 0; ni < 4; ++ni)
            acc[7][ni] = __builtin_amdgcn_mfma_scale_f32_16x16x128_f8f6f4(
                fb, b8[ni], acc[7][ni], 0, 0, 0, 0x7F7F7F7F, 0, 0x7F7F7F7F);
        __builtin_amdgcn_s_setprio(0);
        // next iteration opens with vmcnt + barrier
    }

    // epilogue: per-row max & sum(exp) over this wave's 64 columns
    // C/D layout (16x16): col = lane&15, row = (lane>>4)*4 + reg
    const int chunk = ntile * 4 + wc;
    #pragma unroll
    for (int mi = 0; mi < 8; ++mi) {
        #pragma unroll
        for (int r = 0; r < 4; ++r) {
            float v0 = acc[mi][0][r], v1 = acc[mi][1][r];
            float v2 = acc[mi][2][r], v3 = acc[mi][3][r];
            float mx = fmaxf(fmaxf(v0, v1), fmaxf(v2, v3));
            #pragma unroll
            for (int mask = 1; mask <= 8; mask <<= 1)
                mx = fmaxf(mx, __shfl_xor(mx, mask, 64));
            float sm = __expf(v0 - mx) + __expf(v1 - mx)
                     + __expf(v2 - mx) + __expf(v3 - mx);
            #pragma unroll
            for (int mask = 1; mask <= 8; mask <<= 1)
                sm += __shfl_xor(sm, mask, 64);
            if (c == 0) {
                int row_g = m0 + wr * 128 + mi * 16 + q * 4 + r;
                float* p = partials + ((size_t)row_g * NCHUNK + chunk) * 2;
                p[0] = mx;
                p[1] = sm;
            }
        }
    }
}

// ---------------- fallback GEMM (fp32 in-flight bf16 pack) ----------------

__global__ __launch_bounds__(256, 2)
void gemm_lse_f32(const float* __restrict__ H, const float* __restrict__ W,
                  float* __restrict__ partials) {
    __shared__ unsigned short As[BM][LDK];
    __shared__ unsigned short Bs[BN][LDK];

    const int GM = 8;
    int bid   = blockIdx.x;
    int super = bid / (GM * NTILES);
    int rem   = bid % (GM * NTILES);
    int mtile = super * GM + (rem % GM);
    int ntile = rem / GM;

    const int m0 = mtile * BM;
    const int n0 = ntile * BN;

    const int tid  = threadIdx.x;
    const int lane = tid & 63;
    const int w    = tid >> 6;
    const int wm   = (w >> 1) * 64;
    const int wn   = (w & 1)  * 64;
    const int q    = lane >> 4;
    const int c    = lane & 15;

    f32x4 acc[4][4];
    const f32x4 zero = {0.f, 0.f, 0.f, 0.f};
    #pragma unroll
    for (int i = 0; i < 4; ++i)
        #pragma unroll
        for (int j = 0; j < 4; ++j) acc[i][j] = zero;

    for (int kt = 0; kt < D_MODEL / BK; ++kt) {
        const int k0 = kt * BK;
        #pragma unroll
        for (int s = 0; s < 4; ++s) {
            int i   = tid + s * 256;
            int row = i >> 3;
            int kq  = (i & 7) << 2;

            const float4* pa = (const float4*)(H + (size_t)(m0 + row) * D_MODEL + k0 + kq);
            float4 va = *pa;
            uint2 ba = { pack_bf16(va.x, va.y), pack_bf16(va.z, va.w) };
            *(uint2*)&As[row][kq] = ba;

            const float4* pb = (const float4*)(W + (size_t)(n0 + row) * D_MODEL + k0 + kq);
            float4 vb = *pb;
            uint2 bb = { pack_bf16(vb.x, vb.y), pack_bf16(vb.z, vb.w) };
            *(uint2*)&Bs[row][kq] = bb;
        }
        __syncthreads();

        frag8 af[4], bf[4];
        #pragma unroll
        for (int t = 0; t < 4; ++t)
            af[t] = *(const frag8*)&As[wm + t * 16 + c][q * 8];
        #pragma unroll
        for (int t = 0; t < 4; ++t)
            bf[t] = *(const frag8*)&Bs[wn + t * 16 + c][q * 8];

        #pragma unroll
        for (int tm = 0; tm < 4; ++tm)
            #pragma unroll
            for (int tn = 0; tn < 4; ++tn)
                acc[tm][tn] = __builtin_amdgcn_mfma_f32_16x16x32_bf16(
                    af[tm], bf[tn], acc[tm][tn], 0, 0, 0);
        __syncthreads();
    }

    const int chunk = ntile * 2 + (w & 1);
    #pragma unroll
    for (int tm = 0; tm < 4; ++tm) {
        #pragma unroll
        for (int r = 0; r < 4; ++r) {
            float v0 = acc[tm][0][r], v1 = acc[tm][1][r];
            float v2 = acc[tm][2][r], v3 = acc[tm][3][r];
            float mx = fmaxf(fmaxf(v0, v1), fmaxf(v2, v3));
            #pragma unroll
            for (int mask = 1; mask <= 8; mask <<= 1)
                mx = fmaxf(mx, __shfl_xor(mx, mask, 64));
            float sm = __expf(v0 - mx) + __expf(v1 - mx)
                     + __expf(v2 - mx) + __expf(v3 - mx);
            #pragma unroll
            for (int mask = 1; mask <= 8; mask <<= 1)
                sm += __shfl_xor(sm, mask, 64);
            if (c == 0) {
                int row_g = m0 + wm + tm * 16 + q * 4 + r;
                float* p = partials + ((size_t)row_g * NCHUNK + chunk) * 2;
                p[0] = mx;
                p[1] = sm;
            }
        }
    }
}

// ---------------- aux kernels (no global atomics anywhere) ----------------

// one WAVE per token: exact fp32 dot(h[n], w[target[n]])
__global__ __launch_bounds__(256)
void tgt_kernel(const float* __restrict__ H, const float* __restrict__ W,
                const int* __restrict__ targets, float* __restrict__ tgt_logit) {
    int token = blockIdx.x * 4 + (threadIdx.x >> 6);
    int lane  = threadIdx.x & 63;

    int t  = targets[token];
    int tt = (t == -100) ? 0 : t;
    const float4* h  = (const float4*)(H + (size_t)token * D_MODEL);
    const float4* wr = (const float4*)(W + (size_t)tt * D_MODEL);
    float p = 0.f;
    #pragma unroll
    for (int j = lane; j < D_MODEL / 4; j += 64) {
        float4 a = h[j], b = wr[j];
        p += a.x * b.x + a.y * b.y + a.z * b.z + a.w * b.w;
    }
    #pragma unroll
    for (int mask = 1; mask < 64; mask <<= 1)
        p += __shfl_xor(p, mask, 64);
    if (lane == 0) tgt_logit[token] = p;
}

__device__ inline void lse_merge(float& m, float& s, float om, float os) {
    if (om > m) { s = s * __expf(m - om) + os; m = om; }
    else        { s += os * __expf(om - m); }
}

// one WAVE per token: merge 500 (m,s) chunks -> nll[token]; no atomics
__global__ __launch_bounds__(256)
void reduce_kernel(const float* __restrict__ partials,
                   const float* __restrict__ tgt_logit,
                   const int* __restrict__ targets,
                   float* __restrict__ nll) {
    int token = blockIdx.x * 4 + (threadIdx.x >> 6);
    int lane  = threadIdx.x & 63;

    float m = -INFINITY, s = 0.f;
    const float* base = partials + (size_t)token * NCHUNK * 2;
    for (int ch = lane; ch < NCHUNK; ch += 64) {
        float2 p = ((const float2*)base)[ch];
        lse_merge(m, s, p.x, p.y);
    }
    #pragma unroll
    for (int mask = 1; mask < 64; mask <<= 1) {
        float om = __shfl_xor(m, mask, 64);
        float os = __shfl_xor(s, mask, 64);
        lse_merge(m, s, om, os);
    }
    if (lane == 0) {
        int t = targets[token];
        nll[token] = (t != -100) ? (m + __logf(s) - tgt_logit[token]) : 0.0f;
    }
}

// single block: sum nll + count valid, divide
__global__ __launch_bounds__(256)
void final_kernel(const float* __restrict__ nll, const int* __restrict__ targets,
                  float* __restrict__ out) {
    int tid = threadIdx.x;
    float sum = 0.f, cnt = 0.f;
    for (int i = tid; i < NTOK; i += 256) {
        sum += nll[i];
        cnt += (targets[i] != -100) ? 1.0f : 0.0f;
    }
    #pragma unroll
    for (int mask = 1; mask < 64; mask <<= 1) {
        sum += __shfl_xor(sum, mask, 64);
        cnt += __shfl_xor(cnt, mask, 64);
    }
    __shared__ float lsum[4], lcnt[4];
    int lane = tid & 63, wid = tid >> 6;
    if (lane == 0) { lsum[wid] = sum; lcnt[wid] = cnt; }
    __syncthreads();
    if (tid == 0) {
        float S = lsum[0] + lsum[1] + lsum[2] + lsum[3];
        float C = lcnt[0] + lcnt[1] + lcnt[2] + lcnt[3];
        out[0] = (C > 0.f) ? (S / C) : 0.f;
    }
}

// ---------------- launch ----------------

extern "C" void kernel_launch(void* const* d_in, const int* in_sizes, int n_in,
                              void* d_out, int out_size, void* d_ws, size_t ws_size,
                              hipStream_t stream) {
    (void)in_sizes; (void)n_in; (void)out_size;
    const float* H       = (const float*)d_in[0];   // [4,2048,2048]
    const int*   targets = (const int*)d_in[1];     // [8192]
    const float* W       = (const float*)d_in[2];   // [32000,2048]
    float*       out     = (float*)d_out;

    char* ws = (char*)d_ws;
    const size_t H8_BYTES   = (size_t)NTOK  * D_MODEL;           //  16 MB
    const size_t W8_BYTES   = (size_t)VOCAB * D_MODEL;           //  64 MB
    const size_t PART_BYTES = (size_t)NTOK * NCHUNK * 2 * 4;     //  32 MB
    const size_t NEED = H8_BYTES + W8_BYTES + PART_BYTES + (size_t)NTOK * 8 + 64;

    if (ws_size >= NEED) {
        unsigned char* Hq = (unsigned char*)ws;
        unsigned char* Wq = (unsigned char*)(ws + H8_BYTES);
        float* partials   = (float*)(ws + H8_BYTES + W8_BYTES);
        float* tgt_logit  = (float*)(ws + H8_BYTES + W8_BYTES + PART_BYTES);
        float* nll        = tgt_logit + NTOK;

        static bool attr_done = false;
        if (!attr_done) {
            (void)hipFuncSetAttribute(reinterpret_cast<const void*>(gemm_lse_fp8_v2),
                                      hipFuncAttributeMaxDynamicSharedMemorySize, 131072);
            attr_done = true;
        }

        cvt_fp8_kernel<<<(NTOK  * D_MODEL / 8) / 256, 256, 0, stream>>>(H, Hq);
        cvt_fp8_kernel<<<(VOCAB * D_MODEL / 8) / 256, 256, 0, stream>>>(W, Wq);
        gemm_lse_fp8_v2<<<MT2 * NT2, 512, 131072, stream>>>(Hq, Wq, partials);
        tgt_kernel<<<NTOK / 4, 256, 0, stream>>>(H, W, targets, tgt_logit);
        reduce_kernel<<<NTOK / 4, 256, 0, stream>>>(partials, tgt_logit, targets, nll);
        final_kernel<<<1, 256, 0, stream>>>(nll, targets, out);
    } else {
        float* partials  = (float*)ws;
        float* tgt_logit = (float*)(ws + PART_BYTES);
        float* nll       = tgt_logit + NTOK;

        gemm_lse_f32<<<MTILES * NTILES, 256, 0, stream>>>(H, W, partials);
        tgt_kernel<<<NTOK / 4, 256, 0, stream>>>(H, W, targets, tgt_logit);
        reduce_kernel<<<NTOK / 4, 256, 0, stream>>>(partials, tgt_logit, targets, nll);
        final_kernel<<<1, 256, 0, stream>>>(nll, targets, out);
    }
}